// Round 1
// baseline (4369.930 us; speedup 1.0000x reference)
//
#include <hip/hip_runtime.h>
#include <math.h>

// Problem constants (fixed by the reference)
#define B_ 4
#define T_ 2048
#define D_ 2048
#define L_ 2048
#define KW 4
#define M_ (B_*T_)       // 8192 rows for all GEMMs

// ---------------- SGEMM: C[M,N] = epi(A[M,K] @ B[K,N] + bias[N]) ----------------
#define BM 128
#define BN 128
#define BKT 16
#define LDSS (BM + 4)    // +4 pad: A-store 2-way (free), B-read ~4-way

__device__ __forceinline__ float gelu_exact(float v) {
    return 0.5f * v * (1.0f + erff(v * 0.70710678118654752440f));
}
__device__ __forceinline__ float sigmoidf_(float v) {
    return 1.0f / (1.0f + __expf(-v));
}

template<int EPI>   // 0 = bias only, 1 = gelu, 2 = sigmoid
__global__ __launch_bounds__(256)
void sgemm_kernel(const float* __restrict__ A, const float* __restrict__ Bw,
                  const float* __restrict__ bias, float* __restrict__ C,
                  int M, int N, int K)
{
    __shared__ float As[BKT][LDSS];
    __shared__ float Bs[BKT][LDSS];

    const int tid = threadIdx.x;
    const int bm = blockIdx.y * BM;
    const int bn = blockIdx.x * BN;

    const int tx = tid & 15;        // output col group (8 cols)
    const int ty = tid >> 4;        // output row group (8 rows)

    const int arow = tid >> 2;        // 0..63
    const int acol = (tid & 3) << 2;  // 0,4,8,12
    const int brow = tid >> 5;        // 0..7
    const int bcol = (tid & 31) << 2; // 0..124

    float acc[8][8];
    #pragma unroll
    for (int i = 0; i < 8; ++i)
        #pragma unroll
        for (int j = 0; j < 8; ++j) acc[i][j] = 0.f;

    const float* Aptr0 = A + (size_t)(bm + arow) * K + acol;
    const float* Aptr1 = A + (size_t)(bm + arow + 64) * K + acol;
    const float* Bptr0 = Bw + (size_t)brow * N + bn + bcol;
    const float* Bptr1 = Bw + (size_t)(brow + 8) * N + bn + bcol;

    for (int k0 = 0; k0 < K; k0 += BKT) {
        float4 a0 = *(const float4*)(Aptr0 + k0);
        float4 a1 = *(const float4*)(Aptr1 + k0);
        float4 b0 = *(const float4*)(Bptr0 + (size_t)k0 * N);
        float4 b1 = *(const float4*)(Bptr1 + (size_t)k0 * N);
        __syncthreads();
        As[acol+0][arow]    = a0.x;
        As[acol+1][arow]    = a0.y;
        As[acol+2][arow]    = a0.z;
        As[acol+3][arow]    = a0.w;
        As[acol+0][arow+64] = a1.x;
        As[acol+1][arow+64] = a1.y;
        As[acol+2][arow+64] = a1.z;
        As[acol+3][arow+64] = a1.w;
        *(float4*)&Bs[brow][bcol]   = b0;
        *(float4*)&Bs[brow+8][bcol] = b1;
        __syncthreads();
        #pragma unroll
        for (int kk = 0; kk < BKT; ++kk) {
            float af[8], bf[8];
            *(float4*)&af[0] = *(const float4*)&As[kk][ty*8];
            *(float4*)&af[4] = *(const float4*)&As[kk][ty*8+4];
            *(float4*)&bf[0] = *(const float4*)&Bs[kk][tx*8];
            *(float4*)&bf[4] = *(const float4*)&Bs[kk][tx*8+4];
            #pragma unroll
            for (int i = 0; i < 8; ++i)
                #pragma unroll
                for (int j = 0; j < 8; ++j)
                    acc[i][j] = fmaf(af[i], bf[j], acc[i][j]);
        }
    }

    #pragma unroll
    for (int i = 0; i < 8; ++i) {
        const int row = bm + ty*8 + i;
        float* cp = C + (size_t)row * N + bn + tx*8;
        const float* bp = bias + bn + tx*8;
        float v[8];
        #pragma unroll
        for (int j = 0; j < 8; ++j) {
            float xv = acc[i][j] + bp[j];
            if (EPI == 1)      xv = gelu_exact(xv);
            else if (EPI == 2) xv = sigmoidf_(xv);
            v[j] = xv;
        }
        *(float4*)cp     = *(float4*)&v[0];
        *(float4*)(cp+4) = *(float4*)&v[4];
    }
}

// ---------------- causal depthwise conv1d, width 4 ----------------
// conv[b,t,l] = cb[l] + sum_k cw[k,l] * xb[b, t-3+k, l]   (zero left pad)
__global__ __launch_bounds__(256)
void conv_kernel(const float* __restrict__ xb, const float* __restrict__ cw,
                 const float* __restrict__ cb, float* __restrict__ out)
{
    const int idx = blockIdx.x * 256 + threadIdx.x;   // one float4
    const int NL4 = L_ / 4;
    const int l = (idx % NL4) * 4;
    const int bt = idx / NL4;
    const int t = bt & (T_ - 1);
    float4 acc = *(const float4*)(cb + l);
    #pragma unroll
    for (int k = 0; k < KW; ++k) {
        const int ts = t - (KW-1) + k;
        if (ts >= 0) {
            float4 w = *(const float4*)(cw + k*L_ + l);
            float4 x = *(const float4*)(xb + ((size_t)bt - (KW-1-k)) * L_ + l);
            acc.x = fmaf(w.x, x.x, acc.x);
            acc.y = fmaf(w.y, x.y, acc.y);
            acc.z = fmaf(w.z, x.z, acc.z);
            acc.w = fmaf(w.w, x.w, acc.w);
        }
    }
    *(float4*)(out + (size_t)bt * L_ + l) = acc;
}

// ---------------- RG-LRU pointwise: a, nx from gx, ga, conv ----------------
// in-place: gxa holds sigmoid(conv@w_ig+b) on entry -> holds a on exit
//           ganx holds sigmoid(conv@w_ag+b) on entry -> holds nx on exit
__global__ __launch_bounds__(256)
void rglru_kernel(const float* __restrict__ conv, float* __restrict__ gxa,
                  float* __restrict__ ganx, const float* __restrict__ ap)
{
    const int idx = blockIdx.x * 256 + threadIdx.x;
    const int NL4 = L_ / 4;
    const int l = (idx % NL4) * 4;
    const int bt = idx / NL4;
    const int t = bt & (T_ - 1);
    const size_t off = (size_t)bt * L_ + l;
    float4 gx = *(float4*)(gxa + off);
    float4 ga = *(float4*)(ganx + off);
    float4 cv = *(const float4*)(conv + off);
    float4 apv = *(const float4*)(ap + l);
    float g[4] = {gx.x, gx.y, gx.z, gx.w};
    float q[4] = {ga.x, ga.y, ga.z, ga.w};
    float c[4] = {cv.x, cv.y, cv.z, cv.w};
    float p[4] = {apv.x, apv.y, apv.z, apv.w};
    float av[4], nxv[4];
    #pragma unroll
    for (int j = 0; j < 4; ++j) {
        float sp = log1pf(expf(p[j]));          // softplus(a_param)
        float la = -8.0f * q[j] * sp;           // log_a
        float a  = expf(la);
        float mult = sqrtf(fmaxf(0.f, 1.0f - a*a));  // sqrt(1 - exp(2*log_a))
        if (t == 0) { a = 0.f; mult = 1.f; }
        av[j]  = a;
        nxv[j] = g[j] * c[j] * mult;
    }
    *(float4*)(gxa + off)  = make_float4(av[0], av[1], av[2], av[3]);
    *(float4*)(ganx + off) = make_float4(nxv[0], nxv[1], nxv[2], nxv[3]);
}

// ---------------- chunked linear scan: h_t = a_t*h_{t-1} + x_t ----------------
#define CHUNKS 32
#define CLEN (T_ / CHUNKS)   // 64

// pass 1: per-chunk local scan from h=0; emit product P and local state S
__global__ __launch_bounds__(256)
void scan1_kernel(const float* __restrict__ Ab, const float* __restrict__ Xb,
                  float* __restrict__ Pb, float* __restrict__ Sb)
{
    const int l = blockIdx.x * 256 + threadIdx.x;
    const int c = blockIdx.y;
    const int b = blockIdx.z;
    size_t base = ((size_t)b * T_ + (size_t)c * CLEN) * L_ + l;
    float h = 0.f, P = 1.f;
    #pragma unroll 4
    for (int t = 0; t < CLEN; ++t) {
        float a = Ab[base + (size_t)t * L_];
        float x = Xb[base + (size_t)t * L_];
        h = fmaf(a, h, x);
        P *= a;
    }
    const size_t o = ((size_t)b * CHUNKS + c) * L_ + l;
    Pb[o] = P;
    Sb[o] = h;
}

// pass 2: exclusive scan over chunk states -> carry-in per chunk; final = hn
__global__ __launch_bounds__(256)
void scan2_kernel(const float* __restrict__ Pb, const float* __restrict__ Sb,
                  float* __restrict__ Hin, float* __restrict__ hn)
{
    const int idx = blockIdx.x * 256 + threadIdx.x;  // B*L threads
    const int l = idx & (L_ - 1);
    const int b = idx >> 11;
    float h = 0.f;
    for (int c = 0; c < CHUNKS; ++c) {
        const size_t o = ((size_t)b * CHUNKS + c) * L_ + l;
        Hin[o] = h;
        h = fmaf(Pb[o], h, Sb[o]);
    }
    hn[(size_t)b * L_ + l] = h;
}

// pass 3: re-scan with correct carry-in, fuse z = h*y, write z over Xb
__global__ __launch_bounds__(256)
void scan3_kernel(const float* __restrict__ Ab, float* __restrict__ Xb,
                  const float* __restrict__ Hin, const float* __restrict__ Yb)
{
    const int l = blockIdx.x * 256 + threadIdx.x;
    const int c = blockIdx.y;
    const int b = blockIdx.z;
    float h = Hin[((size_t)b * CHUNKS + c) * L_ + l];
    size_t base = ((size_t)b * T_ + (size_t)c * CLEN) * L_ + l;
    #pragma unroll 4
    for (int t = 0; t < CLEN; ++t) {
        const size_t o = base + (size_t)t * L_;
        float a = Ab[o];
        float x = Xb[o];
        h = fmaf(a, h, x);
        Xb[o] = h * Yb[o];
    }
}

// ---------------- launch ----------------
extern "C" void kernel_launch(void* const* d_in, const int* in_sizes, int n_in,
                              void* d_out, int out_size, void* d_ws, size_t ws_size,
                              hipStream_t stream)
{
    const float* x     = (const float*)d_in[0];
    const float* w_y   = (const float*)d_in[1];
    const float* b_y   = (const float*)d_in[2];
    const float* w_x   = (const float*)d_in[3];
    const float* b_x   = (const float*)d_in[4];
    const float* cw    = (const float*)d_in[5];
    const float* cb    = (const float*)d_in[6];
    const float* ap    = (const float*)d_in[7];
    const float* w_ig  = (const float*)d_in[8];
    const float* b_ig  = (const float*)d_in[9];
    const float* w_ag  = (const float*)d_in[10];
    const float* b_ag  = (const float*)d_in[11];
    const float* w_out = (const float*)d_in[12];
    const float* b_out = (const float*)d_in[13];

    float* out = (float*)d_out;               // [B,T,D] flat
    float* hn  = out + (size_t)M_ * D_;       // [B,L] appended

    // workspace: 3 big f32 buffers [M,L] + 3 small scan buffers [B,CHUNKS,L]
    const size_t SZ = (size_t)M_ * L_ * sizeof(float);
    char* wsc = (char*)d_ws;
    float* ws0 = (float*)(wsc);               // xb -> gx -> a
    float* ws1 = (float*)(wsc + SZ);          // conv
    float* ws2 = (float*)(wsc + 2*SZ);        // ga -> nx -> h*y (z)
    float* Pb  = (float*)(wsc + 3*SZ);
    float* Sb  = Pb + (size_t)B_ * CHUNKS * L_;
    float* Hin = Sb + (size_t)B_ * CHUNKS * L_;

    float* ybuf = out;   // y staged in d_out; consumed by scan3 before final GEMM writes

    const dim3 blk(256);
    const dim3 gGEMM(L_/BN, M_/BM);                 // 16 x 64 = 1024 blocks
    const int nElem4 = (M_ * L_ / 4) / 256;         // elementwise grids
    const dim3 gScan(L_/256, CHUNKS, B_);           // 8 x 32 x 4 = 1024 blocks

    // 1. y = GELU(x@w_y + b_y) -> ybuf (in d_out)
    hipLaunchKernelGGL((sgemm_kernel<1>), gGEMM, blk, 0, stream, x, w_y, b_y, ybuf, M_, L_, D_);
    // 2. xb = x@w_x + b_x -> ws0
    hipLaunchKernelGGL((sgemm_kernel<0>), gGEMM, blk, 0, stream, x, w_x, b_x, ws0, M_, L_, D_);
    // 3. conv(ws0) -> ws1
    hipLaunchKernelGGL(conv_kernel, dim3(nElem4), blk, 0, stream, ws0, cw, cb, ws1);
    // 4. gx = sigmoid(conv@w_ig + b_ig) -> ws0 (xb dead)
    hipLaunchKernelGGL((sgemm_kernel<2>), gGEMM, blk, 0, stream, ws1, w_ig, b_ig, ws0, M_, L_, L_);
    // 5. ga = sigmoid(conv@w_ag + b_ag) -> ws2
    hipLaunchKernelGGL((sgemm_kernel<2>), gGEMM, blk, 0, stream, ws1, w_ag, b_ag, ws2, M_, L_, L_);
    // 6. RG-LRU pointwise: a -> ws0, nx -> ws2 (in place)
    hipLaunchKernelGGL(rglru_kernel, dim3(nElem4), blk, 0, stream, ws1, ws0, ws2, ap);
    // 7-9. chunked scan; pass 3 fuses z = h*y into ws2
    hipLaunchKernelGGL(scan1_kernel, gScan, blk, 0, stream, ws0, ws2, Pb, Sb);
    hipLaunchKernelGGL(scan2_kernel, dim3(B_*L_/256), blk, 0, stream, Pb, Sb, Hin, hn);
    hipLaunchKernelGGL(scan3_kernel, gScan, blk, 0, stream, ws0, ws2, Hin, ybuf);
    // 10. out = z @ w_out + b_out -> d_out
    hipLaunchKernelGGL((sgemm_kernel<0>), gGEMM, blk, 0, stream, ws2, w_out, b_out, out, M_, D_, L_);
}

// Round 2
// 755.058 us; speedup vs baseline: 5.7875x; 5.7875x over previous
//
#include <hip/hip_runtime.h>
#include <math.h>

// Problem constants (fixed by the reference)
#define B_ 4
#define T_ 2048
#define D_ 2048
#define L_ 2048
#define KW 4
#define M_ (B_*T_)       // 8192 rows for all GEMMs

typedef unsigned short u16;
typedef unsigned short u16x8 __attribute__((ext_vector_type(8)));
typedef __bf16 bf16x8 __attribute__((ext_vector_type(8)));
typedef float f32x4 __attribute__((ext_vector_type(4)));

__device__ __forceinline__ u16 f2bf(float f) {       // RNE f32 -> bf16 bits
    unsigned u = __float_as_uint(f);
    u += 0x7fffu + ((u >> 16) & 1u);
    return (u16)(u >> 16);
}
__device__ __forceinline__ float bf2f(u16 h) {
    return __uint_as_float(((unsigned)h) << 16);
}
__device__ __forceinline__ float gelu_exact(float v) {
    return 0.5f * v * (1.0f + erff(v * 0.70710678118654752440f));
}
__device__ __forceinline__ float sigmoidf_(float v) {
    return 1.0f / (1.0f + __expf(-v));
}
__device__ __forceinline__ void gload16(const void* g, void* l) {
    __builtin_amdgcn_global_load_lds(
        (const __attribute__((address_space(1))) void*)g,
        (__attribute__((address_space(3))) void*)l,
        16, 0, 0);
}

// ---------------- cast x -> bf16 ----------------
__global__ __launch_bounds__(256)
void castx_kernel(const float* __restrict__ in, u16* __restrict__ out)
{
    const int i = blockIdx.x * 256 + threadIdx.x;      // one float4
    float4 v = ((const float4*)in)[i];
    ushort4 o;
    o.x = f2bf(v.x); o.y = f2bf(v.y); o.z = f2bf(v.z); o.w = f2bf(v.w);
    ((ushort4*)out)[i] = o;
}

// ---------------- transpose-cast weight [K,N] f32 -> [N,K] bf16 ----------------
__global__ __launch_bounds__(256)
void transcast_kernel(const float* __restrict__ in, u16* __restrict__ out,
                      int Kd, int Nd)
{
    __shared__ float tile[32][33];
    const int bx = blockIdx.x;          // along N
    const int by = blockIdx.y;          // along K
    const int tx = threadIdx.x & 31;
    const int ty = threadIdx.x >> 5;    // 0..7
    #pragma unroll
    for (int j = 0; j < 4; ++j) {
        const int r = by*32 + ty + j*8;
        tile[ty + j*8][tx] = in[(size_t)r * Nd + bx*32 + tx];
    }
    __syncthreads();
    #pragma unroll
    for (int j = 0; j < 4; ++j) {
        const int n = bx*32 + ty + j*8;
        out[(size_t)n * Kd + by*32 + tx] = f2bf(tile[tx][ty + j*8]);
    }
}

// ---------------- bf16 MFMA GEMM: C[M,N] = epi(A[M,K] @ BT[N,K]^T + bias) ----------------
// m97 structure: 128x128 tile, BK=32, 4 waves, global_load_lds(16B), 2 barriers/K-step
__device__ __forceinline__ void store_out(float* C, size_t idx, float v) { C[idx] = v; }
__device__ __forceinline__ void store_out(u16*   C, size_t idx, float v) { C[idx] = f2bf(v); }

template<int EPI, typename OutT>   // EPI: 0 = bias, 1 = gelu, 2 = sigmoid
__global__ __launch_bounds__(256)
void mgemm_kernel(const u16* __restrict__ A, const u16* __restrict__ BT,
                  const float* __restrict__ bias, OutT* __restrict__ C,
                  int M, int N, int K)
{
    __shared__ __align__(16) u16 As[128*32];
    __shared__ __align__(16) u16 Bs[128*32];

    const int tid  = threadIdx.x;
    const int wave = tid >> 6;
    const int lane = tid & 63;
    const int bm = blockIdx.y * 128;
    const int bn = blockIdx.x * 128;

    // staging: chunk q covers As row q/4, k-offset (q%4)*8 (16B per lane)
    const int q0 = wave*128 + lane;        // call 0
    const int q1 = wave*128 + 64 + lane;   // call 1

    const size_t Ag0 = (size_t)(bm + (q0 >> 2)) * K + ((q0 & 3) << 3);
    const size_t Ag1 = (size_t)(bm + (q1 >> 2)) * K + ((q1 & 3) << 3);
    const size_t Bg0 = (size_t)(bn + (q0 >> 2)) * K + ((q0 & 3) << 3);
    const size_t Bg1 = (size_t)(bn + (q1 >> 2)) * K + ((q1 & 3) << 3);

    const int m0 = (wave >> 1) * 64;
    const int n0 = (wave & 1) * 64;
    const int lr = lane & 15;
    const int lk = (lane >> 4) * 8;

    f32x4 acc[4][4] = {};

    for (int k0 = 0; k0 < K; k0 += 32) {
        __syncthreads();
        gload16(A  + Ag0 + k0, &As[q0*8]);
        gload16(A  + Ag1 + k0, &As[q1*8]);
        gload16(BT + Bg0 + k0, &Bs[q0*8]);
        gload16(BT + Bg1 + k0, &Bs[q1*8]);
        __syncthreads();   // drains vmcnt per barrier semantics

        bf16x8 a[4], b[4];
        #pragma unroll
        for (int i = 0; i < 4; ++i)
            a[i] = *(const bf16x8*)&As[(m0 + i*16 + lr)*32 + lk];
        #pragma unroll
        for (int i = 0; i < 4; ++i)
            b[i] = *(const bf16x8*)&Bs[(n0 + i*16 + lr)*32 + lk];
        #pragma unroll
        for (int i = 0; i < 4; ++i)
            #pragma unroll
            for (int j = 0; j < 4; ++j)
                acc[i][j] = __builtin_amdgcn_mfma_f32_16x16x32_bf16(a[i], b[j], acc[i][j], 0, 0, 0);
    }

    // C/D layout: col = lane&15, row = (lane>>4)*4 + reg  [m89-verified]
    const int orow = (lane >> 4) * 4;
    #pragma unroll
    for (int i = 0; i < 4; ++i) {
        #pragma unroll
        for (int j = 0; j < 4; ++j) {
            const int col = bn + n0 + j*16 + lr;
            const float bv = bias[col];
            #pragma unroll
            for (int r = 0; r < 4; ++r) {
                const int row = bm + m0 + i*16 + orow + r;
                float v = acc[i][j][r] + bv;
                if (EPI == 1)      v = gelu_exact(v);
                else if (EPI == 2) v = sigmoidf_(v);
                store_out(C, (size_t)row * N + col, v);
            }
        }
    }
}

// ---------------- causal depthwise conv1d, width 4 (bf16 in/out) ----------------
__global__ __launch_bounds__(256)
void conv_kernel(const u16* __restrict__ xb, const float* __restrict__ cw,
                 const float* __restrict__ cb, u16* __restrict__ out)
{
    const int idx = blockIdx.x * 256 + threadIdx.x;    // one 8-elem chunk
    const int NL8 = L_ / 8;
    const int l = (idx % NL8) * 8;
    const int bt = idx / NL8;
    const int t = bt & (T_ - 1);
    float acc[8];
    #pragma unroll
    for (int j = 0; j < 8; ++j) acc[j] = cb[l + j];
    #pragma unroll
    for (int k = 0; k < KW; ++k) {
        const int ts = t - (KW-1) + k;
        if (ts >= 0) {
            u16x8 xv = *(const u16x8*)(xb + ((size_t)(bt - (KW-1-k))) * L_ + l);
            #pragma unroll
            for (int j = 0; j < 8; ++j)
                acc[j] = fmaf(cw[k*L_ + l + j], bf2f(xv[j]), acc[j]);
        }
    }
    u16x8 o;
    #pragma unroll
    for (int j = 0; j < 8; ++j) o[j] = f2bf(acc[j]);
    *(u16x8*)(out + (size_t)bt * L_ + l) = o;
}

// ---------------- RG-LRU pointwise (in-place: gx->a, ga->nx), bf16 ----------------
__global__ __launch_bounds__(256)
void rglru_kernel(const u16* __restrict__ conv, u16* __restrict__ gxa,
                  u16* __restrict__ ganx, const float* __restrict__ ap)
{
    const int idx = blockIdx.x * 256 + threadIdx.x;
    const int NL8 = L_ / 8;
    const int l = (idx % NL8) * 8;
    const int bt = idx / NL8;
    const int t = bt & (T_ - 1);
    const size_t off = (size_t)bt * L_ + l;
    u16x8 gx = *(u16x8*)(gxa + off);
    u16x8 ga = *(u16x8*)(ganx + off);
    u16x8 cv = *(const u16x8*)(conv + off);
    u16x8 av, nxv;
    #pragma unroll
    for (int j = 0; j < 8; ++j) {
        float p  = ap[l + j];
        float sp = log1pf(expf(p));             // softplus(a_param)
        float la = -8.0f * bf2f(ga[j]) * sp;    // log_a
        float a  = expf(la);
        float mult = sqrtf(fmaxf(0.f, 1.0f - a*a));
        if (t == 0) { a = 0.f; mult = 1.f; }
        av[j]  = f2bf(a);
        nxv[j] = f2bf(bf2f(gx[j]) * bf2f(cv[j]) * mult);
    }
    *(u16x8*)(gxa + off)  = av;
    *(u16x8*)(ganx + off) = nxv;
}

// ---------------- chunked linear scan: h_t = a_t*h_{t-1} + x_t ----------------
#define CHUNKS 32
#define CLEN (T_ / CHUNKS)   // 64

__global__ __launch_bounds__(256)
void scan1_kernel(const u16* __restrict__ Ab, const u16* __restrict__ Xb,
                  float* __restrict__ Pb, float* __restrict__ Sb)
{
    const int l = blockIdx.x * 256 + threadIdx.x;
    const int c = blockIdx.y;
    const int b = blockIdx.z;
    size_t base = ((size_t)b * T_ + (size_t)c * CLEN) * L_ + l;
    float h = 0.f, P = 1.f;
    #pragma unroll 4
    for (int t = 0; t < CLEN; ++t) {
        float a = bf2f(Ab[base + (size_t)t * L_]);
        float x = bf2f(Xb[base + (size_t)t * L_]);
        h = fmaf(a, h, x);
        P *= a;
    }
    const size_t o = ((size_t)b * CHUNKS + c) * L_ + l;
    Pb[o] = P;
    Sb[o] = h;
}

__global__ __launch_bounds__(256)
void scan2_kernel(const float* __restrict__ Pb, const float* __restrict__ Sb,
                  float* __restrict__ Hin, float* __restrict__ hn)
{
    const int idx = blockIdx.x * 256 + threadIdx.x;  // B*L threads
    const int l = idx & (L_ - 1);
    const int b = idx >> 11;
    float h = 0.f;
    for (int c = 0; c < CHUNKS; ++c) {
        const size_t o = ((size_t)b * CHUNKS + c) * L_ + l;
        Hin[o] = h;
        h = fmaf(Pb[o], h, Sb[o]);
    }
    hn[(size_t)b * L_ + l] = h;
}

__global__ __launch_bounds__(256)
void scan3_kernel(const u16* __restrict__ Ab, const u16* __restrict__ Xb,
                  const float* __restrict__ Hin, const u16* __restrict__ Yb,
                  u16* __restrict__ Zb)
{
    const int l = blockIdx.x * 256 + threadIdx.x;
    const int c = blockIdx.y;
    const int b = blockIdx.z;
    float h = Hin[((size_t)b * CHUNKS + c) * L_ + l];
    size_t base = ((size_t)b * T_ + (size_t)c * CLEN) * L_ + l;
    #pragma unroll 4
    for (int t = 0; t < CLEN; ++t) {
        const size_t o = base + (size_t)t * L_;
        h = fmaf(bf2f(Ab[o]), h, bf2f(Xb[o]));
        Zb[o] = f2bf(h * bf2f(Yb[o]));
    }
}

// ---------------- launch ----------------
extern "C" void kernel_launch(void* const* d_in, const int* in_sizes, int n_in,
                              void* d_out, int out_size, void* d_ws, size_t ws_size,
                              hipStream_t stream)
{
    const float* x     = (const float*)d_in[0];
    const float* w_y   = (const float*)d_in[1];
    const float* b_y   = (const float*)d_in[2];
    const float* w_x   = (const float*)d_in[3];
    const float* b_x   = (const float*)d_in[4];
    const float* cw    = (const float*)d_in[5];
    const float* cb    = (const float*)d_in[6];
    const float* ap    = (const float*)d_in[7];
    const float* w_ig  = (const float*)d_in[8];
    const float* b_ig  = (const float*)d_in[9];
    const float* w_ag  = (const float*)d_in[10];
    const float* b_ag  = (const float*)d_in[11];
    const float* w_out = (const float*)d_in[12];
    const float* b_out = (const float*)d_in[13];

    float* out = (float*)d_out;               // [B,T,D] flat
    float* hn  = out + (size_t)M_ * D_;       // [B,L] appended

    // workspace layout (liveness-aliased, peak 192 MB; round-1's 195 MB passed)
    const size_t MB = 1u << 20;
    char* w = (char*)d_ws;
    u16*  xbf   = (u16*)(w + 0);        // [M,D] bf16 — dead after GEMM2
    u16*  wigb  = (u16*)(w + 0);        // [L,L]T bf16 — after xbf dead
    u16*  wagb  = (u16*)(w + 8*MB);
    u16*  zb    = (u16*)(w + 0);        // [M,L] bf16 — after GEMM4
    u16*  ybf   = (u16*)(w + 32*MB);    // [M,L] bf16
    u16*  xbbf  = (u16*)(w + 64*MB);    // [M,L] bf16 — dead after conv
    u16*  woutb = (u16*)(w + 64*MB);    // after xbbf dead
    float* Pb   = (float*)(w + 72*MB);
    float* Sb   = (float*)(w + 73*MB);
    float* Hin  = (float*)(w + 74*MB);
    u16*  wyb   = (u16*)(w + 96*MB);    // weights dead after GEMM2
    u16*  wxb   = (u16*)(w + 104*MB);
    u16*  convb = (u16*)(w + 96*MB);    // [M,L] bf16 — after wyb/wxb dead
    u16*  gx    = (u16*)(w + 128*MB);   // -> a  (in-place)
    u16*  ga    = (u16*)(w + 160*MB);   // -> nx (in-place)

    const dim3 blk(256);
    const dim3 gG(L_/128, M_/128);                  // 16 x 64
    const dim3 gT(2048/32, 2048/32);                // transpose grids
    const int  gE8 = (M_ * L_ / 8) / 256;           // 8-wide elementwise
    const dim3 gScan(L_/256, CHUNKS, B_);

    // casts for stage 1
    hipLaunchKernelGGL(castx_kernel, dim3((M_*D_/4)/256), blk, 0, stream, x, xbf);
    hipLaunchKernelGGL(transcast_kernel, gT, blk, 0, stream, w_y, wyb, D_, L_);
    hipLaunchKernelGGL(transcast_kernel, gT, blk, 0, stream, w_x, wxb, D_, L_);
    // 1. y = GELU(x@w_y + b_y) -> ybf
    hipLaunchKernelGGL((mgemm_kernel<1, u16>), gG, blk, 0, stream, xbf, wyb, b_y, ybf, M_, L_, D_);
    // 2. xb = x@w_x + b_x -> xbbf
    hipLaunchKernelGGL((mgemm_kernel<0, u16>), gG, blk, 0, stream, xbf, wxb, b_x, xbbf, M_, L_, D_);
    // casts for stage 2 (xbf region now dead)
    hipLaunchKernelGGL(transcast_kernel, gT, blk, 0, stream, w_ig, wigb, L_, L_);
    hipLaunchKernelGGL(transcast_kernel, gT, blk, 0, stream, w_ag, wagb, L_, L_);
    // 3. conv(xbbf) -> convb (wyb/wxb region dead)
    hipLaunchKernelGGL(conv_kernel, dim3(gE8), blk, 0, stream, xbbf, cw, cb, convb);
    hipLaunchKernelGGL(transcast_kernel, gT, blk, 0, stream, w_out, woutb, L_, D_);  // xbbf dead
    // 4-5. gates
    hipLaunchKernelGGL((mgemm_kernel<2, u16>), gG, blk, 0, stream, convb, wigb, b_ig, gx, M_, L_, L_);
    hipLaunchKernelGGL((mgemm_kernel<2, u16>), gG, blk, 0, stream, convb, wagb, b_ag, ga, M_, L_, L_);
    // 6. RG-LRU pointwise: a -> gx buf, nx -> ga buf
    hipLaunchKernelGGL(rglru_kernel, dim3(gE8), blk, 0, stream, convb, gx, ga, ap);
    // 7-9. chunked scan; pass 3 fuses z = h*y -> zb (wig/wag region dead)
    hipLaunchKernelGGL(scan1_kernel, gScan, blk, 0, stream, gx, ga, Pb, Sb);
    hipLaunchKernelGGL(scan2_kernel, dim3(B_*L_/256), blk, 0, stream, Pb, Sb, Hin, hn);
    hipLaunchKernelGGL(scan3_kernel, gScan, blk, 0, stream, gx, ga, Hin, ybf, zb);
    // 10. out = z @ w_out + b_out -> d_out (f32)
    hipLaunchKernelGGL((mgemm_kernel<0, float>), gG, blk, 0, stream, zb, woutb, b_out, out, M_, D_, L_);
}

// Round 3
// 585.428 us; speedup vs baseline: 7.4645x; 1.2898x over previous
//
#include <hip/hip_runtime.h>
#include <math.h>

// Problem constants (fixed by the reference)
#define B_ 4
#define T_ 2048
#define D_ 2048
#define L_ 2048
#define KW 4
#define M_ (B_*T_)       // 8192 rows for all GEMMs

typedef unsigned short u16;
typedef unsigned short u16x8 __attribute__((ext_vector_type(8)));
typedef __bf16 bf16x8 __attribute__((ext_vector_type(8)));
typedef float f32x4 __attribute__((ext_vector_type(4)));

__device__ __forceinline__ u16 f2bf(float f) {       // RNE f32 -> bf16 bits
    unsigned u = __float_as_uint(f);
    u += 0x7fffu + ((u >> 16) & 1u);
    return (u16)(u >> 16);
}
__device__ __forceinline__ float bf2f(u16 h) {
    return __uint_as_float(((unsigned)h) << 16);
}
__device__ __forceinline__ float gelu_exact(float v) {
    return 0.5f * v * (1.0f + erff(v * 0.70710678118654752440f));
}
__device__ __forceinline__ float sigmoidf_(float v) {
    return 1.0f / (1.0f + __expf(-v));
}
__device__ __forceinline__ void gload16(const void* g, void* l) {
    __builtin_amdgcn_global_load_lds(
        (const __attribute__((address_space(1))) void*)g,
        (__attribute__((address_space(3))) void*)l,
        16, 0, 0);
}

// ---------------- cast x -> bf16 ----------------
__global__ __launch_bounds__(256)
void castx_kernel(const float* __restrict__ in, u16* __restrict__ out)
{
    const int i = blockIdx.x * 256 + threadIdx.x;      // one float4
    float4 v = ((const float4*)in)[i];
    ushort4 o;
    o.x = f2bf(v.x); o.y = f2bf(v.y); o.z = f2bf(v.z); o.w = f2bf(v.w);
    ((ushort4*)out)[i] = o;
}

// ---------------- transpose-cast weight [K,N] f32 -> [N,K] bf16 ----------------
__global__ __launch_bounds__(256)
void transcast_kernel(const float* __restrict__ in, u16* __restrict__ out,
                      int Kd, int Nd)
{
    __shared__ float tile[32][33];
    const int bx = blockIdx.x;          // along N
    const int by = blockIdx.y;          // along K
    const int tx = threadIdx.x & 31;
    const int ty = threadIdx.x >> 5;    // 0..7
    #pragma unroll
    for (int j = 0; j < 4; ++j) {
        const int r = by*32 + ty + j*8;
        tile[ty + j*8][tx] = in[(size_t)r * Nd + bx*32 + tx];
    }
    __syncthreads();
    #pragma unroll
    for (int j = 0; j < 4; ++j) {
        const int n = bx*32 + ty + j*8;
        out[(size_t)n * Kd + by*32 + tx] = f2bf(tile[tx][ty + j*8]);
    }
}

// =====================================================================
// bf16 MFMA GEMM: C[M,N] = epi(A[M,K] @ BT[N,K]^T + bias)
// 256x128 tile, BK=64, 8 waves (4Mx2N), 512 threads.
// 3-deep LDS pipeline (144 KB), stage-ahead = 2 K-tiles, counted vmcnt(6)
// at tile boundaries (never drained in main loop), raw s_barrier,
// XOR k-slot swizzle (both-sides: pre-swizzled global src + swizzled read),
// setprio(1) around MFMA cluster, bijective XCD block swizzle.
// Safety: slot reuse distance = 3 tiles (>= 2 barriers apart); per-wave
// gload count = 6/tile so vmcnt(6) at boundary t retires exactly tile t+1.
// =====================================================================
__device__ __forceinline__ void store_out(float* C, size_t idx, float v) { C[idx] = v; }
__device__ __forceinline__ void store_out(u16*   C, size_t idx, float v) { C[idx] = f2bf(v); }

#define ASLOT 16384          // 256*64 u16 per A slot
#define BSLOT 8192           // 128*64 u16 per B slot
#define AREG  (3*ASLOT)      // 49152

template<int EPI, typename OutT>   // EPI: 0 = bias, 1 = gelu, 2 = sigmoid
__global__ __launch_bounds__(512)
void mgemm_kernel(const u16* __restrict__ A, const u16* __restrict__ BT,
                  const float* __restrict__ bias, OutT* __restrict__ C,
                  int M, int N, int K)
{
    __shared__ __align__(16) u16 lds[AREG + 3*BSLOT];   // 144 KB

    const int tid  = threadIdx.x;
    const int wave = tid >> 6;          // 0..7
    const int lane = tid & 63;

    // bijective XCD swizzle (nwg % 8 == 0 by construction)
    const int nbx = N >> 7;                       // N/128
    const int nwg = nbx * (M >> 8);               // total blocks
    const int bid = blockIdx.x;
    const int l   = (bid & 7) * (nwg >> 3) + (bid >> 3);
    const int bm  = (l / nbx) * 256;
    const int bn  = (l % nbx) * 128;

    const int wr = wave >> 1;           // 0..3  (M quarter)
    const int wc = wave & 1;            // 0..1  (N half)
    const int lr = lane & 15;
    const int q  = lane >> 4;           // k-quarter within 32
    const int sw = lane & 7;            // read-side swizzle key

    const int grow8 = lane >> 3;              // 0..7 row within chunk
    const int gslot = (lane & 7) ^ grow8;     // pre-swizzled global k-slot

    const int NT = K >> 6;              // K-tiles of 64

    f32x4 acc[4][4] = {};

    // ---- staging: one K-tile = A 32 chunks + B 16 chunks of (8 rows x 128 B);
    //      each wave issues exactly 6 global_load_lds ----
    auto stage = [&](int tt) {
        const size_t kg = (size_t)tt << 6;
        const int slot = tt % 3;
        u16* abase = &lds[slot * ASLOT];
        u16* bbase = &lds[AREG + slot * BSLOT];
        #pragma unroll
        for (int g = 0; g < 4; ++g) {
            const int c = wave*4 + g;                 // 0..31
            gload16(A + (size_t)(bm + c*8 + grow8) * K + kg + gslot*8,
                    &abase[c*512 + lane*8]);
        }
        #pragma unroll
        for (int g = 0; g < 2; ++g) {
            const int c = wave*2 + g;                 // 0..15
            gload16(BT + (size_t)(bn + c*8 + grow8) * K + kg + gslot*8,
                    &bbase[c*512 + lane*8]);
        }
    };

    // prologue: stage tiles 0 and 1; wait for tile 0 only (6 of 12 retire)
    stage(0);
    stage(1);
    asm volatile("s_waitcnt vmcnt(6)" ::: "memory");
    __builtin_amdgcn_s_barrier();
    __builtin_amdgcn_sched_barrier(0);

    for (int t = 0; t < NT; ++t) {
        if (t + 2 < NT) stage(t + 2);

        const int slot = t % 3;
        const u16* ab = &lds[slot * ASLOT];
        const u16* bb = &lds[AREG + slot * BSLOT];

        bf16x8 af[4][2], bfr[4][2];
        #pragma unroll
        for (int i = 0; i < 4; ++i) {
            const int r = wr*64 + i*16 + lr;
            #pragma unroll
            for (int ks = 0; ks < 2; ++ks) {
                const int sk = (ks*4 + q) ^ sw;
                af[i][ks] = *(const bf16x8*)&ab[r*64 + sk*8];
            }
        }
        #pragma unroll
        for (int j = 0; j < 4; ++j) {
            const int r = wc*64 + j*16 + lr;
            #pragma unroll
            for (int ks = 0; ks < 2; ++ks) {
                const int sk = (ks*4 + q) ^ sw;
                bfr[j][ks] = *(const bf16x8*)&bb[r*64 + sk*8];
            }
        }

        __builtin_amdgcn_s_setprio(1);
        #pragma unroll
        for (int i = 0; i < 4; ++i)
            #pragma unroll
            for (int j = 0; j < 4; ++j) {
                acc[i][j] = __builtin_amdgcn_mfma_f32_16x16x32_bf16(af[i][0], bfr[j][0], acc[i][j], 0, 0, 0);
                acc[i][j] = __builtin_amdgcn_mfma_f32_16x16x32_bf16(af[i][1], bfr[j][1], acc[i][j], 0, 0, 0);
            }
        __builtin_amdgcn_s_setprio(0);

        if (t < NT - 1) {
            // tile t+1 was staged >=1 body ago; only tile t+2's 6 loads (if
            // issued this body) may remain outstanding.
            if (t + 2 < NT) asm volatile("s_waitcnt vmcnt(6)" ::: "memory");
            else            asm volatile("s_waitcnt vmcnt(0)" ::: "memory");
            __builtin_amdgcn_s_barrier();
            __builtin_amdgcn_sched_barrier(0);
        }
    }

    // C/D layout: col = lane&15, row = (lane>>4)*4 + reg  [m89-verified]
    const int m0 = wr * 64;
    const int n0 = wc * 64;
    const int orow = (lane >> 4) * 4;
    #pragma unroll
    for (int i = 0; i < 4; ++i) {
        #pragma unroll
        for (int j = 0; j < 4; ++j) {
            const int col = bn + n0 + j*16 + lr;
            const float bv = bias[col];
            #pragma unroll
            for (int r = 0; r < 4; ++r) {
                const int row = bm + m0 + i*16 + orow + r;
                float v = acc[i][j][r] + bv;
                if (EPI == 1)      v = gelu_exact(v);
                else if (EPI == 2) v = sigmoidf_(v);
                store_out(C, (size_t)row * N + col, v);
            }
        }
    }
}

// ---------------- causal depthwise conv1d, width 4 (bf16 in/out) ----------------
__global__ __launch_bounds__(256)
void conv_kernel(const u16* __restrict__ xb, const float* __restrict__ cw,
                 const float* __restrict__ cb, u16* __restrict__ out)
{
    const int idx = blockIdx.x * 256 + threadIdx.x;    // one 8-elem chunk
    const int NL8 = L_ / 8;
    const int l = (idx % NL8) * 8;
    const int bt = idx / NL8;
    const int t = bt & (T_ - 1);
    float acc[8];
    #pragma unroll
    for (int j = 0; j < 8; ++j) acc[j] = cb[l + j];
    #pragma unroll
    for (int k = 0; k < KW; ++k) {
        const int ts = t - (KW-1) + k;
        if (ts >= 0) {
            u16x8 xv = *(const u16x8*)(xb + ((size_t)(bt - (KW-1-k))) * L_ + l);
            #pragma unroll
            for (int j = 0; j < 8; ++j)
                acc[j] = fmaf(cw[k*L_ + l + j], bf2f(xv[j]), acc[j]);
        }
    }
    u16x8 o;
    #pragma unroll
    for (int j = 0; j < 8; ++j) o[j] = f2bf(acc[j]);
    *(u16x8*)(out + (size_t)bt * L_ + l) = o;
}

// ---------------- RG-LRU pointwise (in-place: gx->a, ga->nx), bf16 ----------------
__global__ __launch_bounds__(256)
void rglru_kernel(const u16* __restrict__ conv, u16* __restrict__ gxa,
                  u16* __restrict__ ganx, const float* __restrict__ ap)
{
    const int idx = blockIdx.x * 256 + threadIdx.x;
    const int NL8 = L_ / 8;
    const int l = (idx % NL8) * 8;
    const int bt = idx / NL8;
    const int t = bt & (T_ - 1);
    const size_t off = (size_t)bt * L_ + l;
    u16x8 gx = *(u16x8*)(gxa + off);
    u16x8 ga = *(u16x8*)(ganx + off);
    u16x8 cv = *(const u16x8*)(conv + off);
    u16x8 av, nxv;
    #pragma unroll
    for (int j = 0; j < 8; ++j) {
        float p  = ap[l + j];
        float sp = log1pf(expf(p));             // softplus(a_param)
        float la = -8.0f * bf2f(ga[j]) * sp;    // log_a
        float a  = expf(la);
        float mult = sqrtf(fmaxf(0.f, 1.0f - a*a));
        if (t == 0) { a = 0.f; mult = 1.f; }
        av[j]  = f2bf(a);
        nxv[j] = f2bf(bf2f(gx[j]) * bf2f(cv[j]) * mult);
    }
    *(u16x8*)(gxa + off)  = av;
    *(u16x8*)(ganx + off) = nxv;
}

// ---------------- chunked linear scan: h_t = a_t*h_{t-1} + x_t ----------------
#define CHUNKS 32
#define CLEN (T_ / CHUNKS)   // 64

__global__ __launch_bounds__(256)
void scan1_kernel(const u16* __restrict__ Ab, const u16* __restrict__ Xb,
                  float* __restrict__ Pb, float* __restrict__ Sb)
{
    const int l = blockIdx.x * 256 + threadIdx.x;
    const int c = blockIdx.y;
    const int b = blockIdx.z;
    size_t base = ((size_t)b * T_ + (size_t)c * CLEN) * L_ + l;
    float h = 0.f, P = 1.f;
    #pragma unroll 4
    for (int t = 0; t < CLEN; ++t) {
        float a = bf2f(Ab[base + (size_t)t * L_]);
        float x = bf2f(Xb[base + (size_t)t * L_]);
        h = fmaf(a, h, x);
        P *= a;
    }
    const size_t o = ((size_t)b * CHUNKS + c) * L_ + l;
    Pb[o] = P;
    Sb[o] = h;
}

__global__ __launch_bounds__(256)
void scan2_kernel(const float* __restrict__ Pb, const float* __restrict__ Sb,
                  float* __restrict__ Hin, float* __restrict__ hn)
{
    const int idx = blockIdx.x * 256 + threadIdx.x;  // B*L threads
    const int l = idx & (L_ - 1);
    const int b = idx >> 11;
    float h = 0.f;
    for (int c = 0; c < CHUNKS; ++c) {
        const size_t o = ((size_t)b * CHUNKS + c) * L_ + l;
        Hin[o] = h;
        h = fmaf(Pb[o], h, Sb[o]);
    }
    hn[(size_t)b * L_ + l] = h;
}

__global__ __launch_bounds__(256)
void scan3_kernel(const u16* __restrict__ Ab, const u16* __restrict__ Xb,
                  const float* __restrict__ Hin, const u16* __restrict__ Yb,
                  u16* __restrict__ Zb)
{
    const int l = blockIdx.x * 256 + threadIdx.x;
    const int c = blockIdx.y;
    const int b = blockIdx.z;
    float h = Hin[((size_t)b * CHUNKS + c) * L_ + l];
    size_t base = ((size_t)b * T_ + (size_t)c * CLEN) * L_ + l;
    #pragma unroll 4
    for (int t = 0; t < CLEN; ++t) {
        const size_t o = base + (size_t)t * L_;
        h = fmaf(bf2f(Ab[o]), h, bf2f(Xb[o]));
        Zb[o] = f2bf(h * bf2f(Yb[o]));
    }
}

// ---------------- launch ----------------
extern "C" void kernel_launch(void* const* d_in, const int* in_sizes, int n_in,
                              void* d_out, int out_size, void* d_ws, size_t ws_size,
                              hipStream_t stream)
{
    const float* x     = (const float*)d_in[0];
    const float* w_y   = (const float*)d_in[1];
    const float* b_y   = (const float*)d_in[2];
    const float* w_x   = (const float*)d_in[3];
    const float* b_x   = (const float*)d_in[4];
    const float* cw    = (const float*)d_in[5];
    const float* cb    = (const float*)d_in[6];
    const float* ap    = (const float*)d_in[7];
    const float* w_ig  = (const float*)d_in[8];
    const float* b_ig  = (const float*)d_in[9];
    const float* w_ag  = (const float*)d_in[10];
    const float* b_ag  = (const float*)d_in[11];
    const float* w_out = (const float*)d_in[12];
    const float* b_out = (const float*)d_in[13];

    float* out = (float*)d_out;               // [B,T,D] flat
    float* hn  = out + (size_t)M_ * D_;       // [B,L] appended

    // workspace layout (liveness-aliased, peak 192 MB)
    const size_t MB = 1u << 20;
    char* w = (char*)d_ws;
    u16*  xbf   = (u16*)(w + 0);        // [M,D] bf16 — dead after GEMM2
    u16*  wigb  = (u16*)(w + 0);        // [L,L]T bf16 — after xbf dead
    u16*  wagb  = (u16*)(w + 8*MB);
    u16*  zb    = (u16*)(w + 0);        // [M,L] bf16 — after GEMM4
    u16*  ybf   = (u16*)(w + 32*MB);    // [M,L] bf16
    u16*  xbbf  = (u16*)(w + 64*MB);    // [M,L] bf16 — dead after conv
    u16*  woutb = (u16*)(w + 64*MB);    // after xbbf dead
    float* Pb   = (float*)(w + 72*MB);
    float* Sb   = (float*)(w + 73*MB);
    float* Hin  = (float*)(w + 74*MB);
    u16*  wyb   = (u16*)(w + 96*MB);    // weights dead after GEMM2
    u16*  wxb   = (u16*)(w + 104*MB);
    u16*  convb = (u16*)(w + 96*MB);    // [M,L] bf16 — after wyb/wxb dead
    u16*  gx    = (u16*)(w + 128*MB);   // -> a  (in-place)
    u16*  ga    = (u16*)(w + 160*MB);   // -> nx (in-place)

    const dim3 blk(256);
    const dim3 blkG(512);
    const dim3 gG((L_/128) * (M_/256));             // 512 blocks, 1-D
    const dim3 gT(2048/32, 2048/32);                // transpose grids
    const int  gE8 = (M_ * L_ / 8) / 256;           // 8-wide elementwise
    const dim3 gScan(L_/256, CHUNKS, B_);

    // casts for stage 1
    hipLaunchKernelGGL(castx_kernel, dim3((M_*D_/4)/256), blk, 0, stream, x, xbf);
    hipLaunchKernelGGL(transcast_kernel, gT, blk, 0, stream, w_y, wyb, D_, L_);
    hipLaunchKernelGGL(transcast_kernel, gT, blk, 0, stream, w_x, wxb, D_, L_);
    // 1. y = GELU(x@w_y + b_y) -> ybf
    hipLaunchKernelGGL((mgemm_kernel<1, u16>), gG, blkG, 0, stream, xbf, wyb, b_y, ybf, M_, L_, D_);
    // 2. xb = x@w_x + b_x -> xbbf
    hipLaunchKernelGGL((mgemm_kernel<0, u16>), gG, blkG, 0, stream, xbf, wxb, b_x, xbbf, M_, L_, D_);
    // casts for stage 2 (xbf region now dead)
    hipLaunchKernelGGL(transcast_kernel, gT, blk, 0, stream, w_ig, wigb, L_, L_);
    hipLaunchKernelGGL(transcast_kernel, gT, blk, 0, stream, w_ag, wagb, L_, L_);
    // 3. conv(xbbf) -> convb (wyb/wxb region dead)
    hipLaunchKernelGGL(conv_kernel, dim3(gE8), blk, 0, stream, xbbf, cw, cb, convb);
    hipLaunchKernelGGL(transcast_kernel, gT, blk, 0, stream, w_out, woutb, L_, D_);  // xbbf dead
    // 4-5. gates
    hipLaunchKernelGGL((mgemm_kernel<2, u16>), gG, blkG, 0, stream, convb, wigb, b_ig, gx, M_, L_, L_);
    hipLaunchKernelGGL((mgemm_kernel<2, u16>), gG, blkG, 0, stream, convb, wagb, b_ag, ga, M_, L_, L_);
    // 6. RG-LRU pointwise: a -> gx buf, nx -> ga buf
    hipLaunchKernelGGL(rglru_kernel, dim3(gE8), blk, 0, stream, convb, gx, ga, ap);
    // 7-9. chunked scan; pass 3 fuses z = h*y -> zb (wig/wag region dead)
    hipLaunchKernelGGL(scan1_kernel, gScan, blk, 0, stream, gx, ga, Pb, Sb);
    hipLaunchKernelGGL(scan2_kernel, dim3(B_*L_/256), blk, 0, stream, Pb, Sb, Hin, hn);
    hipLaunchKernelGGL(scan3_kernel, gScan, blk, 0, stream, gx, ga, Hin, ybf, zb);
    // 10. out = z @ w_out + b_out -> d_out (f32)
    hipLaunchKernelGGL((mgemm_kernel<0, float>), gG, blkG, 0, stream, zb, woutb, b_out, out, M_, D_, L_);
}

// Round 4
// 570.539 us; speedup vs baseline: 7.6593x; 1.0261x over previous
//
#include <hip/hip_runtime.h>
#include <math.h>

// Problem constants (fixed by the reference)
#define B_ 4
#define T_ 2048
#define D_ 2048
#define L_ 2048
#define KW 4
#define M_ (B_*T_)       // 8192 rows for all GEMMs

typedef unsigned short u16;
typedef unsigned short u16x8 __attribute__((ext_vector_type(8)));
typedef __bf16 bf16x8 __attribute__((ext_vector_type(8)));
typedef float f32x4 __attribute__((ext_vector_type(4)));

__device__ __forceinline__ u16 f2bf(float f) {       // RNE f32 -> bf16 bits
    unsigned u = __float_as_uint(f);
    u += 0x7fffu + ((u >> 16) & 1u);
    return (u16)(u >> 16);
}
__device__ __forceinline__ float bf2f(u16 h) {
    return __uint_as_float(((unsigned)h) << 16);
}
__device__ __forceinline__ float gelu_exact(float v) {
    return 0.5f * v * (1.0f + erff(v * 0.70710678118654752440f));
}
__device__ __forceinline__ float sigmoidf_(float v) {
    return 1.0f / (1.0f + __expf(-v));
}
__device__ __forceinline__ void gload16(const void* g, void* l) {
    __builtin_amdgcn_global_load_lds(
        (const __attribute__((address_space(1))) void*)g,
        (__attribute__((address_space(3))) void*)l,
        16, 0, 0);
}

// ---------------- cast x -> bf16 ----------------
__global__ __launch_bounds__(256)
void castx_kernel(const float* __restrict__ in, u16* __restrict__ out)
{
    const int i = blockIdx.x * 256 + threadIdx.x;      // one float4
    float4 v = ((const float4*)in)[i];
    ushort4 o;
    o.x = f2bf(v.x); o.y = f2bf(v.y); o.z = f2bf(v.z); o.w = f2bf(v.w);
    ((ushort4*)out)[i] = o;
}

// ---------------- transpose-cast weight [K,N] f32 -> [N,K] bf16 ----------------
__global__ __launch_bounds__(256)
void transcast_kernel(const float* __restrict__ in, u16* __restrict__ out,
                      int Kd, int Nd)
{
    __shared__ float tile[32][33];
    const int bx = blockIdx.x;          // along N
    const int by = blockIdx.y;          // along K
    const int tx = threadIdx.x & 31;
    const int ty = threadIdx.x >> 5;    // 0..7
    #pragma unroll
    for (int j = 0; j < 4; ++j) {
        const int r = by*32 + ty + j*8;
        tile[ty + j*8][tx] = in[(size_t)r * Nd + bx*32 + tx];
    }
    __syncthreads();
    #pragma unroll
    for (int j = 0; j < 4; ++j) {
        const int n = bx*32 + ty + j*8;
        out[(size_t)n * Kd + by*32 + tx] = f2bf(tile[tx][ty + j*8]);
    }
}

// =====================================================================
// bf16 MFMA GEMM: C[M,N] = epi(A[M,K] @ BT[N,K]^T + bias)
// 256x256 tile, BK=64, 8 waves (2M x 4N), per-wave 128x64, 512 threads.
// m201-style 4-phase-per-K-tile schedule: each phase = {ds_read subtile |
// stage 1 half-tile (2 gload_lds) | barrier | lgkmcnt(0)+sched_barrier |
// setprio(1) 16 MFMA setprio(0) | barrier}. Quadrant order (m0n0, m0n1,
// m1n1, m1n0) gives each LDS sub-region a single read phase -> freed
// progressively -> staging runs 3 half-tiles ahead with ONE vmcnt(6) per
// K-tile (drain-0 only at the tail). LDS 128 KB double-buffer; XOR k-slot
// swizzle on both sides (verified 0 conflicts); bijective XCD swizzle.
// In-flight ledger (per wave, 2 loads per half-tile):
//   prologue: stage kt0{AH0,BH0,BH1,AH1} + kt1{AH0,BH0,BH1} = 14 loads,
//   vmcnt(6) retires kt0's 8. Group g: P1 stages AH1(g+1), P2 AH0(g+2),
//   P3 BH0(g+2), P4 BH1(g+2); at P4 end outstanding=14, vmcnt(6) retires
//   exactly kt(g+1)'s 8. Tail: group NT-2 ends vmcnt(0).
// =====================================================================
__device__ __forceinline__ void store_out(float* C, size_t idx, float v) { C[idx] = v; }
__device__ __forceinline__ void store_out(u16*   C, size_t idx, float v) { C[idx] = f2bf(v); }

#define LD_A(Abp, MH) do { _Pragma("unroll") for (int ii = 0; ii < 4; ++ii) { \
    af[ii][0] = *(const bf16x8*)&(Abp)[ar[ii] + (MH)*4096 + ks0]; \
    af[ii][1] = *(const bf16x8*)&(Abp)[ar[ii] + (MH)*4096 + ks1]; } } while(0)

#define LD_B(Bbp, NH, DST) do { _Pragma("unroll") for (int jj = 0; jj < 2; ++jj) { \
    DST[jj][0] = *(const bf16x8*)&(Bbp)[br[jj] + (NH)*2048 + ks0]; \
    DST[jj][1] = *(const bf16x8*)&(Bbp)[br[jj] + (NH)*2048 + ks1]; } } while(0)

#define MM(MH, NH, BFR) do { \
    _Pragma("unroll") for (int ii = 0; ii < 4; ++ii) \
    _Pragma("unroll") for (int jj = 0; jj < 2; ++jj) \
        acc[(MH)*4+ii][(NH)*2+jj] = __builtin_amdgcn_mfma_f32_16x16x32_bf16(af[ii][0], BFR[jj][0], acc[(MH)*4+ii][(NH)*2+jj], 0, 0, 0); \
    _Pragma("unroll") for (int ii = 0; ii < 4; ++ii) \
    _Pragma("unroll") for (int jj = 0; jj < 2; ++jj) \
        acc[(MH)*4+ii][(NH)*2+jj] = __builtin_amdgcn_mfma_f32_16x16x32_bf16(af[ii][1], BFR[jj][1], acc[(MH)*4+ii][(NH)*2+jj], 0, 0, 0); \
} while(0)

#define ST_AH0(bufp, kge) { gload16(gA0 + (kge), &(bufp)[dA0]); gload16(gA1 + (kge), &(bufp)[dA1]); }
#define ST_AH1(bufp, kge) { gload16(gA2 + (kge), &(bufp)[dA2]); gload16(gA3 + (kge), &(bufp)[dA3]); }
#define ST_BH0(bufp, kge) { gload16(gB0 + (kge), &(bufp)[dB0]); gload16(gB1 + (kge), &(bufp)[dB1]); }
#define ST_BH1(bufp, kge) { gload16(gB2 + (kge), &(bufp)[dB2]); gload16(gB3 + (kge), &(bufp)[dB3]); }

#define BAR()   __builtin_amdgcn_s_barrier()
#define LGKM0() do { asm volatile("s_waitcnt lgkmcnt(0)" ::: "memory"); \
                     __builtin_amdgcn_sched_barrier(0); } while(0)

template<int EPI, typename OutT>   // EPI: 0 = bias, 1 = gelu, 2 = sigmoid
__global__ __launch_bounds__(512)
void mgemm_kernel(const u16* __restrict__ A, const u16* __restrict__ BT,
                  const float* __restrict__ bias, OutT* __restrict__ C,
                  int M, int N, int K)
{
    __shared__ __align__(16) u16 lds[65536];   // [A: 2 x 16384][B: 2 x 16384] = 128 KB
    u16* ldsB = lds + 32768;

    const int tid  = threadIdx.x;
    const int wave = tid >> 6;          // 0..7
    const int lane = tid & 63;

    // bijective XCD swizzle (nwg = 256, %8 == 0)
    const int nbx = N >> 8;                       // N/256
    const int nwg = nbx * (M >> 8);
    const int bid = blockIdx.x;
    const int li  = (bid & 7) * (nwg >> 3) + (bid >> 3);
    const int bm  = (li / nbx) * 256;
    const int bn  = (li % nbx) * 256;

    const int wm = wave >> 2;           // 0..1  (M half)
    const int wn = wave & 3;            // 0..3  (N quarter)
    const int lr = lane & 15;
    const int q  = lane >> 4;           // k-quarter within 32
    const int sw = lane & 7;            // read-side swizzle key

    const int grow8 = lane >> 3;              // row within 8-row chunk
    const int gslot = (lane & 7) ^ grow8;     // pre-swizzled global k-slot

    const int NT = K >> 6;              // K-tiles of 64 (=32 here)

    // ---- staging sources: A half-tiles AH0={chunks w,16+w}, AH1={8+w,24+w};
    //      B: bc=(w&3)+(w>>2)*8, BH0={bc,bc+16}, BH1={bc+4,bc+20} ----
    const int bc = (wave & 3) + (wave >> 2) * 8;
    const u16* gA0 = A  + (size_t)(bm + (wave     )*8 + grow8) * K + gslot*8;
    const u16* gA1 = A  + (size_t)(bm + (wave + 16)*8 + grow8) * K + gslot*8;
    const u16* gA2 = A  + (size_t)(bm + (wave +  8)*8 + grow8) * K + gslot*8;
    const u16* gA3 = A  + (size_t)(bm + (wave + 24)*8 + grow8) * K + gslot*8;
    const u16* gB0 = BT + (size_t)(bn + (bc       )*8 + grow8) * K + gslot*8;
    const u16* gB1 = BT + (size_t)(bn + (bc  + 16 )*8 + grow8) * K + gslot*8;
    const u16* gB2 = BT + (size_t)(bn + (bc  +  4 )*8 + grow8) * K + gslot*8;
    const u16* gB3 = BT + (size_t)(bn + (bc  + 20 )*8 + grow8) * K + gslot*8;
    const int dA0 = (wave     )*512 + lane*8, dA1 = (wave + 16)*512 + lane*8;
    const int dA2 = (wave +  8)*512 + lane*8, dA3 = (wave + 24)*512 + lane*8;
    const int dB0 = (bc       )*512 + lane*8, dB1 = (bc  + 16 )*512 + lane*8;
    const int dB2 = (bc  +  4 )*512 + lane*8, dB3 = (bc  + 20 )*512 + lane*8;

    // ---- read offsets (elems); swizzled slot: global slot s at row r lives
    //      at LDS slot s^(r&7); r&7 == sw for all our rows ----
    int ar[4], br[2];
    #pragma unroll
    for (int i = 0; i < 4; ++i) ar[i] = (wm*128 + i*16 + lr) * 64;
    #pragma unroll
    for (int j = 0; j < 2; ++j) br[j] = (wn*64  + j*16 + lr) * 64;
    const int ks0 = ((    q) ^ sw) * 8;
    const int ks1 = ((4 + q) ^ sw) * 8;

    f32x4 acc[8][4] = {};
    bf16x8 af[4][2], bf0[2][2], bf1[2][2];

    // ---- prologue: kt0 complete + kt1 {AH0,BH0,BH1}; retire kt0 ----
    {
        u16* A0 = lds;          u16* B0 = ldsB;
        u16* A1 = lds + 16384;  u16* B1 = ldsB + 16384;
        ST_AH0(A0, 0); ST_BH0(B0, 0); ST_BH1(B0, 0); ST_AH1(A0, 0);
        ST_AH0(A1, 64); ST_BH0(B1, 64); ST_BH1(B1, 64);
        asm volatile("s_waitcnt vmcnt(6)" ::: "memory");
        BAR();
    }

    for (int g = 0; g < NT; ++g) {
        const int buf = g & 1;
        u16* Ab  = lds  + buf*16384;
        u16* Bb  = ldsB + buf*16384;
        u16* AbN = lds  + (buf^1)*16384;
        const size_t kg1 = (size_t)(g+1) << 6;
        const size_t kg2 = (size_t)(g+2) << 6;
        const bool s1 = (g + 1 < NT), s2 = (g + 2 < NT);

        // ---- P1 (m-half 0, n-half 0): read AH0 + BH0; stage AH1(g+1) ----
        LD_A(Ab, 0);
        LD_B(Bb, 0, bf0);
        if (s1) ST_AH1(AbN, kg1);
        BAR();
        LGKM0();
        __builtin_amdgcn_s_setprio(1);
        MM(0, 0, bf0);
        __builtin_amdgcn_s_setprio(0);
        BAR();

        // ---- P2 (m0, n1): read BH1; stage AH0(g+2) into CURRENT buf ----
        LD_B(Bb, 1, bf1);
        if (s2) ST_AH0(Ab, kg2);
        BAR();
        LGKM0();
        __builtin_amdgcn_s_setprio(1);
        MM(0, 1, bf1);
        __builtin_amdgcn_s_setprio(0);
        BAR();

        // ---- P3 (m1, n1): read AH1 (overwrite af); stage BH0(g+2) ----
        LD_A(Ab, 1);
        if (s2) ST_BH0(Bb, kg2);
        BAR();
        LGKM0();
        __builtin_amdgcn_s_setprio(1);
        MM(1, 1, bf1);
        __builtin_amdgcn_s_setprio(0);
        BAR();

        // ---- P4 (m1, n0): pure-reg MFMA; stage BH1(g+2); K-tile vmcnt ----
        if (s2) ST_BH1(Bb, kg2);
        BAR();
        __builtin_amdgcn_s_setprio(1);
        MM(1, 0, bf0);
        __builtin_amdgcn_s_setprio(0);
        if (s2)      { asm volatile("s_waitcnt vmcnt(6)" ::: "memory"); }
        else if (s1) { asm volatile("s_waitcnt vmcnt(0)" ::: "memory"); }
        BAR();
    }

    // ---- epilogue; C/D layout: col = lane&15, row = (lane>>4)*4 + reg ----
    const int orow = (lane >> 4) * 4;
    #pragma unroll
    for (int nj = 0; nj < 4; ++nj) {
        const int col = bn + wn*64 + nj*16 + lr;
        const float bv = bias[col];
        #pragma unroll
        for (int mi = 0; mi < 8; ++mi) {
            const int row0 = bm + wm*128 + mi*16 + orow;
            #pragma unroll
            for (int r = 0; r < 4; ++r) {
                float v = acc[mi][nj][r] + bv;
                if (EPI == 1)      v = gelu_exact(v);
                else if (EPI == 2) v = sigmoidf_(v);
                store_out(C, (size_t)(row0 + r) * N + col, v);
            }
        }
    }
}

// ---------------- causal depthwise conv1d, width 4 (bf16 in/out) ----------------
__global__ __launch_bounds__(256)
void conv_kernel(const u16* __restrict__ xb, const float* __restrict__ cw,
                 const float* __restrict__ cb, u16* __restrict__ out)
{
    const int idx = blockIdx.x * 256 + threadIdx.x;    // one 8-elem chunk
    const int NL8 = L_ / 8;
    const int l = (idx % NL8) * 8;
    const int bt = idx / NL8;
    const int t = bt & (T_ - 1);
    float acc[8];
    #pragma unroll
    for (int j = 0; j < 8; ++j) acc[j] = cb[l + j];
    #pragma unroll
    for (int k = 0; k < KW; ++k) {
        const int ts = t - (KW-1) + k;
        if (ts >= 0) {
            u16x8 xv = *(const u16x8*)(xb + ((size_t)(bt - (KW-1-k))) * L_ + l);
            #pragma unroll
            for (int j = 0; j < 8; ++j)
                acc[j] = fmaf(cw[k*L_ + l + j], bf2f(xv[j]), acc[j]);
        }
    }
    u16x8 o;
    #pragma unroll
    for (int j = 0; j < 8; ++j) o[j] = f2bf(acc[j]);
    *(u16x8*)(out + (size_t)bt * L_ + l) = o;
}

// ---------------- RG-LRU pointwise (in-place: gx->a, ga->nx), bf16 ----------------
__global__ __launch_bounds__(256)
void rglru_kernel(const u16* __restrict__ conv, u16* __restrict__ gxa,
                  u16* __restrict__ ganx, const float* __restrict__ ap)
{
    const int idx = blockIdx.x * 256 + threadIdx.x;
    const int NL8 = L_ / 8;
    const int l = (idx % NL8) * 8;
    const int bt = idx / NL8;
    const int t = bt & (T_ - 1);
    const size_t off = (size_t)bt * L_ + l;
    u16x8 gx = *(u16x8*)(gxa + off);
    u16x8 ga = *(u16x8*)(ganx + off);
    u16x8 cv = *(const u16x8*)(conv + off);
    u16x8 av, nxv;
    #pragma unroll
    for (int j = 0; j < 8; ++j) {
        float p  = ap[l + j];
        float sp = log1pf(expf(p));             // softplus(a_param)
        float la = -8.0f * bf2f(ga[j]) * sp;    // log_a
        float a  = expf(la);
        float mult = sqrtf(fmaxf(0.f, 1.0f - a*a));
        if (t == 0) { a = 0.f; mult = 1.f; }
        av[j]  = f2bf(a);
        nxv[j] = f2bf(bf2f(gx[j]) * bf2f(cv[j]) * mult);
    }
    *(u16x8*)(gxa + off)  = av;
    *(u16x8*)(ganx + off) = nxv;
}

// ---------------- chunked linear scan: h_t = a_t*h_{t-1} + x_t ----------------
#define CHUNKS 32
#define CLEN (T_ / CHUNKS)   // 64

__global__ __launch_bounds__(256)
void scan1_kernel(const u16* __restrict__ Ab, const u16* __restrict__ Xb,
                  float* __restrict__ Pb, float* __restrict__ Sb)
{
    const int l = blockIdx.x * 256 + threadIdx.x;
    const int c = blockIdx.y;
    const int b = blockIdx.z;
    size_t base = ((size_t)b * T_ + (size_t)c * CLEN) * L_ + l;
    float h = 0.f, P = 1.f;
    #pragma unroll 4
    for (int t = 0; t < CLEN; ++t) {
        float a = bf2f(Ab[base + (size_t)t * L_]);
        float x = bf2f(Xb[base + (size_t)t * L_]);
        h = fmaf(a, h, x);
        P *= a;
    }
    const size_t o = ((size_t)b * CHUNKS + c) * L_ + l;
    Pb[o] = P;
    Sb[o] = h;
}

__global__ __launch_bounds__(256)
void scan2_kernel(const float* __restrict__ Pb, const float* __restrict__ Sb,
                  float* __restrict__ Hin, float* __restrict__ hn)
{
    const int idx = blockIdx.x * 256 + threadIdx.x;  // B*L threads
    const int l = idx & (L_ - 1);
    const int b = idx >> 11;
    float h = 0.f;
    for (int c = 0; c < CHUNKS; ++c) {
        const size_t o = ((size_t)b * CHUNKS + c) * L_ + l;
        Hin[o] = h;
        h = fmaf(Pb[o], h, Sb[o]);
    }
    hn[(size_t)b * L_ + l] = h;
}

__global__ __launch_bounds__(256)
void scan3_kernel(const u16* __restrict__ Ab, const u16* __restrict__ Xb,
                  const float* __restrict__ Hin, const u16* __restrict__ Yb,
                  u16* __restrict__ Zb)
{
    const int l = blockIdx.x * 256 + threadIdx.x;
    const int c = blockIdx.y;
    const int b = blockIdx.z;
    float h = Hin[((size_t)b * CHUNKS + c) * L_ + l];
    size_t base = ((size_t)b * T_ + (size_t)c * CLEN) * L_ + l;
    #pragma unroll 4
    for (int t = 0; t < CLEN; ++t) {
        const size_t o = base + (size_t)t * L_;
        h = fmaf(bf2f(Ab[o]), h, bf2f(Xb[o]));
        Zb[o] = f2bf(h * bf2f(Yb[o]));
    }
}

// ---------------- launch ----------------
extern "C" void kernel_launch(void* const* d_in, const int* in_sizes, int n_in,
                              void* d_out, int out_size, void* d_ws, size_t ws_size,
                              hipStream_t stream)
{
    const float* x     = (const float*)d_in[0];
    const float* w_y   = (const float*)d_in[1];
    const float* b_y   = (const float*)d_in[2];
    const float* w_x   = (const float*)d_in[3];
    const float* b_x   = (const float*)d_in[4];
    const float* cw    = (const float*)d_in[5];
    const float* cb    = (const float*)d_in[6];
    const float* ap    = (const float*)d_in[7];
    const float* w_ig  = (const float*)d_in[8];
    const float* b_ig  = (const float*)d_in[9];
    const float* w_ag  = (const float*)d_in[10];
    const float* b_ag  = (const float*)d_in[11];
    const float* w_out = (const float*)d_in[12];
    const float* b_out = (const float*)d_in[13];

    float* out = (float*)d_out;               // [B,T,D] flat
    float* hn  = out + (size_t)M_ * D_;       // [B,L] appended

    // workspace layout (liveness-aliased, peak 192 MB)
    const size_t MB = 1u << 20;
    char* w = (char*)d_ws;
    u16*  xbf   = (u16*)(w + 0);        // [M,D] bf16 — dead after GEMM2
    u16*  wigb  = (u16*)(w + 0);        // [L,L]T bf16 — after xbf dead
    u16*  wagb  = (u16*)(w + 8*MB);
    u16*  zb    = (u16*)(w + 0);        // [M,L] bf16 — after GEMM4
    u16*  ybf   = (u16*)(w + 32*MB);    // [M,L] bf16
    u16*  xbbf  = (u16*)(w + 64*MB);    // [M,L] bf16 — dead after conv
    u16*  woutb = (u16*)(w + 64*MB);    // after xbbf dead
    float* Pb   = (float*)(w + 72*MB);
    float* Sb   = (float*)(w + 73*MB);
    float* Hin  = (float*)(w + 74*MB);
    u16*  wyb   = (u16*)(w + 96*MB);    // weights dead after GEMM2
    u16*  wxb   = (u16*)(w + 104*MB);
    u16*  convb = (u16*)(w + 96*MB);    // [M,L] bf16 — after wyb/wxb dead
    u16*  gx    = (u16*)(w + 128*MB);   // -> a  (in-place)
    u16*  ga    = (u16*)(w + 160*MB);   // -> nx (in-place)

    const dim3 blk(256);
    const dim3 blkG(512);
    const dim3 gG((L_/256) * (M_/256));             // 256 blocks = 1/CU
    const dim3 gT(2048/32, 2048/32);                // transpose grids
    const int  gE8 = (M_ * L_ / 8) / 256;           // 8-wide elementwise
    const dim3 gScan(L_/256, CHUNKS, B_);

    // casts for stage 1
    hipLaunchKernelGGL(castx_kernel, dim3((M_*D_/4)/256), blk, 0, stream, x, xbf);
    hipLaunchKernelGGL(transcast_kernel, gT, blk, 0, stream, w_y, wyb, D_, L_);
    hipLaunchKernelGGL(transcast_kernel, gT, blk, 0, stream, w_x, wxb, D_, L_);
    // 1. y = GELU(x@w_y + b_y) -> ybf
    hipLaunchKernelGGL((mgemm_kernel<1, u16>), gG, blkG, 0, stream, xbf, wyb, b_y, ybf, M_, L_, D_);
    // 2. xb = x@w_x + b_x -> xbbf
    hipLaunchKernelGGL((mgemm_kernel<0, u16>), gG, blkG, 0, stream, xbf, wxb, b_x, xbbf, M_, L_, D_);
    // casts for stage 2 (xbf region now dead)
    hipLaunchKernelGGL(transcast_kernel, gT, blk, 0, stream, w_ig, wigb, L_, L_);
    hipLaunchKernelGGL(transcast_kernel, gT, blk, 0, stream, w_ag, wagb, L_, L_);
    // 3. conv(xbbf) -> convb (wyb/wxb region dead)
    hipLaunchKernelGGL(conv_kernel, dim3(gE8), blk, 0, stream, xbbf, cw, cb, convb);
    hipLaunchKernelGGL(transcast_kernel, gT, blk, 0, stream, w_out, woutb, L_, D_);  // xbbf dead
    // 4-5. gates
    hipLaunchKernelGGL((mgemm_kernel<2, u16>), gG, blkG, 0, stream, convb, wigb, b_ig, gx, M_, L_, L_);
    hipLaunchKernelGGL((mgemm_kernel<2, u16>), gG, blkG, 0, stream, convb, wagb, b_ag, ga, M_, L_, L_);
    // 6. RG-LRU pointwise: a -> gx buf, nx -> ga buf
    hipLaunchKernelGGL(rglru_kernel, dim3(gE8), blk, 0, stream, convb, gx, ga, ap);
    // 7-9. chunked scan; pass 3 fuses z = h*y -> zb (wig/wag region dead)
    hipLaunchKernelGGL(scan1_kernel, gScan, blk, 0, stream, gx, ga, Pb, Sb);
    hipLaunchKernelGGL(scan2_kernel, dim3(B_*L_/256), blk, 0, stream, Pb, Sb, Hin, hn);
    hipLaunchKernelGGL(scan3_kernel, gScan, blk, 0, stream, gx, ga, Hin, ybf, zb);
    // 10. out = z @ w_out + b_out -> d_out (f32)
    hipLaunchKernelGGL((mgemm_kernel<0, float>), gG, blkG, 0, stream, zb, woutb, b_out, out, M_, D_, L_);
}